// Round 12
// baseline (43.446 us; speedup 1.0000x reference)
//
#include <hip/hip_runtime.h>
#include <math.h>

// Problem constants
#define BB 512      // batch (edges)
#define NN 4096     // nodes
#define LL 128      // feature dim
#define IN_DIM 385  // 3*L + ND
#define NK4_1 97    // ceil(IN_DIM/4) k-groups, layer 1
#define NK4_2 32    // LL/4 k-groups, layer 2 / GRU
#define GPB 2       // nodes per block (gru kernel)

// ---------------------------------------------------------------------------
// Workspace layout (float offsets, float4-aligned)
// ---------------------------------------------------------------------------
#define OFF_MSG   0                           // msg_sum (N*L)
#define OFF_CNT   (OFF_MSG + NN * LL)         // cnt (N)
#define OFF_COUNT (OFF_CNT + NN)              // seen_count (1 int) + pad
#define OFF_LIST  (OFF_COUNT + 4)             // seen list (1024 ints)
#define OFF_W1PS  529416                      // src_w1 packed f4[k4*128+j]
#define OFF_W1PT  (OFF_W1PS + NK4_1 * LL * 4)
#define OFF_W2PS  (OFF_W1PT + NK4_1 * LL * 4)
#define OFF_W2PT  (OFF_W2PS + NK4_2 * LL * 4)
#define OFF_WIHP  (OFF_W2PT + NK4_2 * LL * 4) // f4[(gate*32+k4)*128+j]
#define OFF_WHHP  (OFF_WIHP + 3 * NK4_2 * LL * 4)

// ---------------------------------------------------------------------------
// Prep: zero accumulators + pack ALL weights f4[k4*128+j] (lane-coalesced).
// Identical to r9 (proven).
// ---------------------------------------------------------------------------
__global__ __launch_bounds__(256) void prep_kernel(
    const float* __restrict__ sw1, const float* __restrict__ tw1,
    const float* __restrict__ sw2, const float* __restrict__ tw2,
    const float* __restrict__ wih, const float* __restrict__ whh,
    float* __restrict__ ws)
{
    const int i = blockIdx.x * 256 + threadIdx.x;
    const int stride = gridDim.x * 256;

    float4* msg4 = (float4*)(ws + OFF_MSG);
    const float4 z4 = make_float4(0.f, 0.f, 0.f, 0.f);
    for (int idx = i; idx < NN * LL / 4; idx += stride)
        msg4[idx] = z4;
    for (int idx = i; idx < NN; idx += stride)
        ws[OFF_CNT + idx] = 0.0f;
    if (i == 0)
        ((int*)ws)[OFF_COUNT] = 0;

    float4* w1ps = (float4*)(ws + OFF_W1PS);
    float4* w1pt = (float4*)(ws + OFF_W1PT);
    for (int idx = i; idx < NK4_1 * LL; idx += stride) {
        const int k4 = idx >> 7, j = idx & 127;
        const int k = k4 * 4;
        float4 a, b;
        a.x = sw1[j * IN_DIM + k];     b.x = tw1[j * IN_DIM + k];
        a.y = (k + 1 < IN_DIM) ? sw1[j * IN_DIM + k + 1] : 0.f;
        b.y = (k + 1 < IN_DIM) ? tw1[j * IN_DIM + k + 1] : 0.f;
        a.z = (k + 2 < IN_DIM) ? sw1[j * IN_DIM + k + 2] : 0.f;
        b.z = (k + 2 < IN_DIM) ? tw1[j * IN_DIM + k + 2] : 0.f;
        a.w = (k + 3 < IN_DIM) ? sw1[j * IN_DIM + k + 3] : 0.f;
        b.w = (k + 3 < IN_DIM) ? tw1[j * IN_DIM + k + 3] : 0.f;
        w1ps[idx] = a; w1pt[idx] = b;
    }
    float4* w2ps = (float4*)(ws + OFF_W2PS);
    float4* w2pt = (float4*)(ws + OFF_W2PT);
    for (int idx = i; idx < NK4_2 * LL; idx += stride) {
        const int k4 = idx >> 7, j = idx & 127;
        const int k = k4 * 4;
        w2ps[idx] = make_float4(sw2[j * LL + k], sw2[j * LL + k + 1],
                                sw2[j * LL + k + 2], sw2[j * LL + k + 3]);
        w2pt[idx] = make_float4(tw2[j * LL + k], tw2[j * LL + k + 1],
                                tw2[j * LL + k + 2], tw2[j * LL + k + 3]);
    }
    float4* wihp = (float4*)(ws + OFF_WIHP);
    float4* whhp = (float4*)(ws + OFF_WHHP);
    for (int idx = i; idx < 3 * NK4_2 * LL; idx += stride) {
        const int j = idx & 127;
        const int gk = idx >> 7;
        const int gate = gk >> 5, k4 = gk & 31;
        const int row = gate * LL + j, k = k4 * 4;
        wihp[idx] = make_float4(wih[row * LL + k], wih[row * LL + k + 1],
                                wih[row * LL + k + 2], wih[row * LL + k + 3]);
        whhp[idx] = make_float4(whh[row * LL + k], whh[row * LL + k + 1],
                                whh[row * LL + k + 2], whh[row * LL + k + 3]);
    }
}

// ---------------------------------------------------------------------------
// Edge messages: EPB=1 -- one block per (edge, side). 1024 blocks (4/CU,
// 16 waves/CU) + 32 copy blocks. 256 threads = 2 k-groups x 128 features.
// Block-uniform operand reads (no staging), packed lane-coalesced weights.
// ---------------------------------------------------------------------------
__global__ __launch_bounds__(256) void edge_msg_kernel(
    const float* __restrict__ x,        // (B, N, 1)
    const float* __restrict__ memory,   // (N, L)
    const float* __restrict__ delta_t,  // (B, N, L)
    const float* __restrict__ sb1, const float* __restrict__ sb2,
    const float* __restrict__ tb1, const float* __restrict__ tb2,
    const int* __restrict__ source, const int* __restrict__ target,
    float* __restrict__ ws, float* __restrict__ out)
{
    const int tid = threadIdx.x;

    // ---- copy blocks ----
    if (blockIdx.x >= 1024) {
        const int cb = blockIdx.x - 1024;
        float4* out4 = (float4*)out;
        const float4* mem4 = (const float4*)memory;
        for (int idx = cb * 256 + tid; idx < NN * LL / 4; idx += 32 * 256)
            out4[idx] = mem4[idx];
        return;
    }

    // ---- edge blocks: one (edge, side) task ----
    const int side = blockIdx.x & 1;
    const int eg   = blockIdx.x >> 1;
    const int g    = tid >> 7;               // k-split group 0/1
    const int j    = tid & 127;              // output feature

    const int s = source[eg], t = target[eg];
    const int node  = side ? t : s;
    const int other = side ? s : t;

    __shared__ float h1[LL];
    __shared__ float part1[2][LL];
    __shared__ float part2[2][LL];

    const float4* w1p = (const float4*)(ws + (side ? OFF_W1PT : OFF_W1PS));
    const float4* w2p = (const float4*)(ws + (side ? OFF_W2PT : OFF_W2PS));
    const float* b1  = side ? tb1 : sb1;
    const float* b2  = side ? tb2 : sb2;

    // Layer 1, segment-split 48/49:
    //   g0: mem[node] k4 [0,32) + mem[other] k4 [32,48)
    //   g1: mem[other] k4 [48,64) + delta_t k4 [64,96) + x (k4 96)
    {
        float a0 = 0.f;
        if (g == 0) {
            const float* p = memory + (size_t)node * LL;
            #pragma unroll 4
            for (int k4 = 0; k4 < 32; ++k4) {
                const float4 w = w1p[k4 * LL + j];
                const float4 v = *(const float4*)(p + 4 * k4);
                a0 = fmaf(w.x, v.x, a0); a0 = fmaf(w.y, v.y, a0);
                a0 = fmaf(w.z, v.z, a0); a0 = fmaf(w.w, v.w, a0);
            }
            const float* q = memory + (size_t)other * LL;
            #pragma unroll 4
            for (int k4 = 32; k4 < 48; ++k4) {
                const float4 w = w1p[k4 * LL + j];
                const float4 v = *(const float4*)(q + 4 * (k4 - 32));
                a0 = fmaf(w.x, v.x, a0); a0 = fmaf(w.y, v.y, a0);
                a0 = fmaf(w.z, v.z, a0); a0 = fmaf(w.w, v.w, a0);
            }
        } else {
            const float* q = memory + (size_t)other * LL;
            #pragma unroll 4
            for (int k4 = 48; k4 < 64; ++k4) {
                const float4 w = w1p[k4 * LL + j];
                const float4 v = *(const float4*)(q + 4 * (k4 - 32));
                a0 = fmaf(w.x, v.x, a0); a0 = fmaf(w.y, v.y, a0);
                a0 = fmaf(w.z, v.z, a0); a0 = fmaf(w.w, v.w, a0);
            }
            const float* d = delta_t + ((size_t)eg * NN + node) * LL;
            #pragma unroll 4
            for (int k4 = 64; k4 < 96; ++k4) {
                const float4 w = w1p[k4 * LL + j];
                const float4 v = *(const float4*)(d + 4 * (k4 - 64));
                a0 = fmaf(w.x, v.x, a0); a0 = fmaf(w.y, v.y, a0);
                a0 = fmaf(w.z, v.z, a0); a0 = fmaf(w.w, v.w, a0);
            }
            {   // k = 384: x (w1p[96].yzw zero-padded)
                const float4 w = w1p[96 * LL + j];
                a0 = fmaf(w.x, x[(size_t)eg * NN + node], a0);
            }
        }
        part1[g][j] = a0;
    }
    __syncthreads();

    // Combine + bias + relu (first 128 threads).
    if (g == 0)
        h1[j] = fmaxf(part1[0][j] + part1[1][j] + b1[j], 0.0f);
    __syncthreads();

    // Layer 2: g0 -> k4 [0,16), g1 -> [16,32)
    {
        const int k40 = g * 16, k41 = k40 + 16;
        float a0 = 0.f;
        #pragma unroll 4
        for (int k4 = k40; k4 < k41; ++k4) {
            const float4 w = w2p[k4 * LL + j];
            const float4 hA = *(const float4*)&h1[k4 * 4];
            a0 = fmaf(w.x, hA.x, a0); a0 = fmaf(w.y, hA.y, a0);
            a0 = fmaf(w.z, hA.z, a0); a0 = fmaf(w.w, hA.w, a0);
        }
        part2[g][j] = a0;
    }
    __syncthreads();

    // Final message; atomic segment-sum (first 128 threads).
    if (g == 0) {
        const float m = part2[0][j] + part2[1][j] + b2[j];
        atomicAdd(ws + OFF_MSG + (size_t)node * LL + j, m);
    }
    if (tid == 0) {
        const float old = atomicAdd(ws + OFF_CNT + node, 1.0f);
        if (old == 0.0f) {
            const int pos = atomicAdd((int*)ws + OFF_COUNT, 1);
            ((int*)ws)[OFF_LIST + pos] = node;
        }
    }
}

// ---------------------------------------------------------------------------
// GRU over the compact seen list. GPB=2 nodes/block, 512 blocks (2/CU),
// 256 threads, gate-split (g0: wih vs raw msg_sum end-scaled; g1: whh vs h).
// ---------------------------------------------------------------------------
__global__ __launch_bounds__(256) void gru_kernel(
    const float* __restrict__ memory,
    const float* __restrict__ bih, const float* __restrict__ bhh,
    const float* __restrict__ ws, float* __restrict__ out)
{
    const int tid = threadIdx.x;
    const int g = tid >> 7, j = tid & 127;
    const int scount = ((const int*)ws)[OFF_COUNT];
    const int base = blockIdx.x * GPB;
    if (base >= scount) return;
    const int nact = min(GPB, scount - base);

    __shared__ float gates[6][GPB][LL];      // 6 KB
    __shared__ int   nodes_sh[GPB];

    int nd[GPB];
    #pragma unroll
    for (int s = 0; s < GPB; ++s)
        nd[s] = (base + s < scount) ? ((const int*)ws)[OFF_LIST + base + s]
                                    : ((const int*)ws)[OFF_LIST + base];
    if (tid < GPB) nodes_sh[tid] = nd[tid];

    const float* op[GPB];
    float rc[GPB] = {1.f, 1.f};
    #pragma unroll
    for (int s = 0; s < GPB; ++s) {
        if (g == 0) {
            op[s] = ws + OFF_MSG + (size_t)nd[s] * LL;
            rc[s] = 1.0f / ws[OFF_CNT + nd[s]];
        } else {
            op[s] = memory + (size_t)nd[s] * LL;
        }
    }

    const float4* wp = (const float4*)(ws + (g ? OFF_WHHP : OFF_WIHP));
    float a0[GPB] = {}, a1[GPB] = {}, a2[GPB] = {};
    #pragma unroll 2
    for (int k4 = 0; k4 < NK4_2; ++k4) {
        const float4 w0 = wp[(0 * NK4_2 + k4) * LL + j];
        const float4 w1 = wp[(1 * NK4_2 + k4) * LL + j];
        const float4 w2 = wp[(2 * NK4_2 + k4) * LL + j];
        #pragma unroll
        for (int s = 0; s < GPB; ++s) {
            const float4 v = *(const float4*)(op[s] + 4 * k4);
            a0[s] = fmaf(w0.x, v.x, a0[s]); a0[s] = fmaf(w0.y, v.y, a0[s]);
            a0[s] = fmaf(w0.z, v.z, a0[s]); a0[s] = fmaf(w0.w, v.w, a0[s]);
            a1[s] = fmaf(w1.x, v.x, a1[s]); a1[s] = fmaf(w1.y, v.y, a1[s]);
            a1[s] = fmaf(w1.z, v.z, a1[s]); a1[s] = fmaf(w1.w, v.w, a1[s]);
            a2[s] = fmaf(w2.x, v.x, a2[s]); a2[s] = fmaf(w2.y, v.y, a2[s]);
            a2[s] = fmaf(w2.z, v.z, a2[s]); a2[s] = fmaf(w2.w, v.w, a2[s]);
        }
    }
    #pragma unroll
    for (int s = 0; s < GPB; ++s) {
        gates[g * 3 + 0][s][j] = a0[s] * rc[s];
        gates[g * 3 + 1][s][j] = a1[s] * rc[s];
        gates[g * 3 + 2][s][j] = a2[s] * rc[s];
    }
    __syncthreads();

    // Finalize; h re-read coalesced from global (L2 hit).
    const int total = nact * LL;
    for (int o = tid; o < total; o += 256) {
        const int s = o >> 7, jj = o & 127;
        const int node = nodes_sh[s];
        const float ir = gates[0][s][jj] + bih[jj];
        const float iz = gates[1][s][jj] + bih[LL + jj];
        const float inn = gates[2][s][jj] + bih[2 * LL + jj];
        const float hr = gates[3][s][jj] + bhh[jj];
        const float hz = gates[4][s][jj] + bhh[LL + jj];
        const float hn = gates[5][s][jj] + bhh[2 * LL + jj];
        const float r = 1.0f / (1.0f + __expf(-(ir + hr)));
        const float z = 1.0f / (1.0f + __expf(-(iz + hz)));
        const float n = tanhf(inn + r * hn);
        const float h = memory[(size_t)node * LL + jj];
        out[(size_t)node * LL + jj] = (1.0f - z) * n + z * h;
    }
}

// ---------------------------------------------------------------------------
extern "C" void kernel_launch(void* const* d_in, const int* in_sizes, int n_in,
                              void* d_out, int out_size, void* d_ws, size_t ws_size,
                              hipStream_t stream) {
    const float* x        = (const float*)d_in[0];
    const float* memory   = (const float*)d_in[1];
    const float* delta_t  = (const float*)d_in[2];
    const float* src_w1   = (const float*)d_in[3];
    const float* src_b1   = (const float*)d_in[4];
    const float* src_w2   = (const float*)d_in[5];
    const float* src_b2   = (const float*)d_in[6];
    const float* tar_w1   = (const float*)d_in[7];
    const float* tar_b1   = (const float*)d_in[8];
    const float* tar_w2   = (const float*)d_in[9];
    const float* tar_b2   = (const float*)d_in[10];
    const float* gru_wih  = (const float*)d_in[11];
    const float* gru_whh  = (const float*)d_in[12];
    const float* gru_bih  = (const float*)d_in[13];
    const float* gru_bhh  = (const float*)d_in[14];
    const int*   source   = (const int*)d_in[15];
    const int*   target   = (const int*)d_in[16];

    float* out = (float*)d_out;
    float* ws  = (float*)d_ws;

    // 1) prep: zero accumulators + pack all weights
    prep_kernel<<<512, 256, 0, stream>>>(
        src_w1, tar_w1, src_w2, tar_w2, gru_wih, gru_whh, ws);

    // 2) edge messages (1024 blocks, EPB=1) + memory->out copy (32 blocks)
    edge_msg_kernel<<<1056, 256, 0, stream>>>(
        x, memory, delta_t, src_b1, src_b2, tar_b1, tar_b2,
        source, target, ws, out);

    // 3) GRU over compact seen list (512 blocks, GPB=2)
    gru_kernel<<<1024 / GPB, 256, 0, stream>>>(
        memory, gru_bih, gru_bhh, ws, out);
}

// Round 13
// 34.965 us; speedup vs baseline: 1.2426x; 1.2426x over previous
//
#include <hip/hip_runtime.h>
#include <math.h>

// Problem constants
#define BB 512      // batch (edges)
#define NN 4096     // nodes
#define LL 128      // feature dim
#define IN_DIM 385  // 3*L + ND
#define NK8_1 49    // ceil(IN_DIM/8) k-groups, layer 1 (8 bf16 per load)
#define NK8_2 16    // LL/8 k-groups, layer 2 / GRU
#define EPB 2       // edges per block (edge kernel)
#define GPB 4       // nodes per block (gru kernel)

// ---------------------------------------------------------------------------
// Workspace layout (float/u32 offsets, 16B-aligned)
// ---------------------------------------------------------------------------
#define OFF_MSG   0                            // msg_sum (N*L) f32
#define OFF_CNT   (OFF_MSG + NN * LL)          // cnt (N)
#define OFF_COUNT (OFF_CNT + NN)               // seen_count (1 int) + pad
#define OFF_LIST  (OFF_COUNT + 4)              // seen list (1024 ints)
#define OFF_W1BS  529416                       // src w1 bf16: uint4[k8*128+j]
#define OFF_W1BT  (OFF_W1BS + NK8_1 * LL * 4)
#define OFF_W2BS  (OFF_W1BT + NK8_1 * LL * 4)
#define OFF_W2BT  (OFF_W2BS + NK8_2 * LL * 4)
#define OFF_WIHB  (OFF_W2BT + NK8_2 * LL * 4)  // uint4[(gate*16+k8)*128+j]
#define OFF_WHHB  (OFF_WIHB + 3 * NK8_2 * LL * 4)
// end = 645128 floats ~ 2.58 MB

// ---------------------------------------------------------------------------
// bf16 helpers
// ---------------------------------------------------------------------------
__device__ inline unsigned short f2bf(float f) {          // RNE round
    unsigned u = __float_as_uint(f);
    return (unsigned short)((u + 0x7fffu + ((u >> 16) & 1u)) >> 16);
}
__device__ inline unsigned pack2(float lo, float hi) {
    return (unsigned)f2bf(lo) | ((unsigned)f2bf(hi) << 16);
}
struct f8 { float v[8]; };
__device__ inline f8 unpack8(uint4 u) {                   // 8 bf16 -> f32
    f8 r;
    r.v[0] = __uint_as_float(u.x << 16); r.v[1] = __uint_as_float(u.x & 0xffff0000u);
    r.v[2] = __uint_as_float(u.y << 16); r.v[3] = __uint_as_float(u.y & 0xffff0000u);
    r.v[4] = __uint_as_float(u.z << 16); r.v[5] = __uint_as_float(u.z & 0xffff0000u);
    r.v[6] = __uint_as_float(u.w << 16); r.v[7] = __uint_as_float(u.w & 0xffff0000u);
    return r;
}

// ---------------------------------------------------------------------------
// Prep: zero accumulators + pack ALL weights as bf16 uint4[k8*128 + j]
// (lane-coalesced: consecutive j = consecutive 16B).
// ---------------------------------------------------------------------------
__global__ __launch_bounds__(256) void prep_kernel(
    const float* __restrict__ sw1, const float* __restrict__ tw1,
    const float* __restrict__ sw2, const float* __restrict__ tw2,
    const float* __restrict__ wih, const float* __restrict__ whh,
    float* __restrict__ ws)
{
    const int i = blockIdx.x * 256 + threadIdx.x;
    const int stride = gridDim.x * 256;

    float4* msg4 = (float4*)(ws + OFF_MSG);
    const float4 z4 = make_float4(0.f, 0.f, 0.f, 0.f);
    for (int idx = i; idx < NN * LL / 4; idx += stride)
        msg4[idx] = z4;
    for (int idx = i; idx < NN; idx += stride)
        ws[OFF_CNT + idx] = 0.0f;
    if (i == 0)
        ((int*)ws)[OFF_COUNT] = 0;

    // layer-1: (L, IN=385) -> bf16x8 blocks, zero-padded to 392
    uint4* w1bs = (uint4*)(ws + OFF_W1BS);
    uint4* w1bt = (uint4*)(ws + OFF_W1BT);
    for (int idx = i; idx < NK8_1 * LL; idx += stride) {
        const int k8 = idx >> 7, j = idx & 127;
        const int k = k8 * 8;
        float a[8], b[8];
        #pragma unroll
        for (int c = 0; c < 8; ++c) {
            a[c] = (k + c < IN_DIM) ? sw1[j * IN_DIM + k + c] : 0.f;
            b[c] = (k + c < IN_DIM) ? tw1[j * IN_DIM + k + c] : 0.f;
        }
        w1bs[idx] = make_uint4(pack2(a[0], a[1]), pack2(a[2], a[3]),
                               pack2(a[4], a[5]), pack2(a[6], a[7]));
        w1bt[idx] = make_uint4(pack2(b[0], b[1]), pack2(b[2], b[3]),
                               pack2(b[4], b[5]), pack2(b[6], b[7]));
    }
    // layer-2: (L, L)
    uint4* w2bs = (uint4*)(ws + OFF_W2BS);
    uint4* w2bt = (uint4*)(ws + OFF_W2BT);
    for (int idx = i; idx < NK8_2 * LL; idx += stride) {
        const int k8 = idx >> 7, j = idx & 127;
        const int k = k8 * 8;
        const float* pa = sw2 + j * LL + k;
        const float* pb = tw2 + j * LL + k;
        w2bs[idx] = make_uint4(pack2(pa[0], pa[1]), pack2(pa[2], pa[3]),
                               pack2(pa[4], pa[5]), pack2(pa[6], pa[7]));
        w2bt[idx] = make_uint4(pack2(pb[0], pb[1]), pack2(pb[2], pb[3]),
                               pack2(pb[4], pb[5]), pack2(pb[6], pb[7]));
    }
    // GRU: (3L, L) -> uint4[(gate*16 + k8)*L + j]
    uint4* wihb = (uint4*)(ws + OFF_WIHB);
    uint4* whhb = (uint4*)(ws + OFF_WHHB);
    for (int idx = i; idx < 3 * NK8_2 * LL; idx += stride) {
        const int j = idx & 127;
        const int gk = idx >> 7;             // gate*16 + k8
        const int gate = gk >> 4, k8 = gk & 15;
        const float* pa = wih + (gate * LL + j) * LL + k8 * 8;
        const float* pb = whh + (gate * LL + j) * LL + k8 * 8;
        wihb[idx] = make_uint4(pack2(pa[0], pa[1]), pack2(pa[2], pa[3]),
                               pack2(pa[4], pa[5]), pack2(pa[6], pa[7]));
        whhb[idx] = make_uint4(pack2(pb[0], pb[1]), pack2(pb[2], pb[3]),
                               pack2(pb[4], pb[5]), pack2(pb[6], pb[7]));
    }
}

// One bf16x8 weight block against two edges' 8 input floats.
#define BF8_STEP(WU, A0, A1, B0, B1) {                                  \
    const f8 W_ = unpack8(WU);                                          \
    a0 = fmaf(W_.v[0], (A0).x, a0); a1 = fmaf(W_.v[0], (B0).x, a1);     \
    a0 = fmaf(W_.v[1], (A0).y, a0); a1 = fmaf(W_.v[1], (B0).y, a1);     \
    a0 = fmaf(W_.v[2], (A0).z, a0); a1 = fmaf(W_.v[2], (B0).z, a1);     \
    a0 = fmaf(W_.v[3], (A0).w, a0); a1 = fmaf(W_.v[3], (B0).w, a1);     \
    a0 = fmaf(W_.v[4], (A1).x, a0); a1 = fmaf(W_.v[4], (B1).x, a1);     \
    a0 = fmaf(W_.v[5], (A1).y, a0); a1 = fmaf(W_.v[5], (B1).y, a1);     \
    a0 = fmaf(W_.v[6], (A1).z, a0); a1 = fmaf(W_.v[6], (B1).z, a1);     \
    a0 = fmaf(W_.v[7], (A1).w, a0); a1 = fmaf(W_.v[7], (B1).w, a1); }

// ---------------------------------------------------------------------------
// Edge messages: r9 structure (EPB=2, destaged block-uniform operand reads),
// bf16 weights (half the loads, half the bytes). Blocks >=512: copy.
// ---------------------------------------------------------------------------
__global__ __launch_bounds__(256) void edge_msg_kernel(
    const float* __restrict__ x,        // (B, N, 1)
    const float* __restrict__ memory,   // (N, L)
    const float* __restrict__ delta_t,  // (B, N, L)
    const float* __restrict__ sb1, const float* __restrict__ sb2,
    const float* __restrict__ tb1, const float* __restrict__ tb2,
    const int* __restrict__ source, const int* __restrict__ target,
    float* __restrict__ ws, float* __restrict__ out)
{
    const int tid = threadIdx.x;

    // ---- copy blocks ----
    if (blockIdx.x >= 512) {
        const int cb = blockIdx.x - 512;
        float4* out4 = (float4*)out;
        const float4* mem4 = (const float4*)memory;
        for (int idx = cb * 256 + tid; idx < NN * LL / 4; idx += 32 * 256)
            out4[idx] = mem4[idx];
        return;
    }

    // ---- edge blocks ----
    const int side  = blockIdx.x & 1;
    const int chunk = blockIdx.x >> 1;
    const int g     = tid >> 7;              // k-split group
    const int j     = tid & 127;             // output feature

    const int eg0 = chunk * EPB, eg1 = eg0 + 1;
    const int s0 = source[eg0], t0 = target[eg0];
    const int s1 = source[eg1], t1 = target[eg1];
    const int node0  = side ? t0 : s0, other0 = side ? s0 : t0;
    const int node1  = side ? t1 : s1, other1 = side ? s1 : t1;

    __shared__ float h1s[EPB][LL];
    __shared__ float part1[2][EPB][LL];
    __shared__ float part2[2][EPB][LL];

    const uint4* w1b = (const uint4*)(ws + (side ? OFF_W1BT : OFF_W1BS));
    const uint4* w2b = (const uint4*)(ws + (side ? OFF_W2BT : OFF_W2BS));
    const float* b1  = side ? tb1 : sb1;
    const float* b2  = side ? tb2 : sb2;

    // Layer 1, k8 segments: [0,16)=mem[node], [16,32)=mem[other],
    // [32,48)=delta_t, 48=x. Split g0 [0,24), g1 [24,49).
    {
        float a0 = 0.f, a1 = 0.f;
        const float* nA = memory + (size_t)node0 * LL;
        const float* nB = memory + (size_t)node1 * LL;
        const float* oA = memory + (size_t)other0 * LL;
        const float* oB = memory + (size_t)other1 * LL;
        const float* dA = delta_t + ((size_t)eg0 * NN + node0) * LL;
        const float* dB = delta_t + ((size_t)eg1 * NN + node1) * LL;

        if (g == 0) {
            #pragma unroll 4
            for (int k8 = 0; k8 < 16; ++k8) {
                const uint4 wu = w1b[k8 * LL + j];
                const float4 A0 = *(const float4*)(nA + 8 * k8);
                const float4 A1 = *(const float4*)(nA + 8 * k8 + 4);
                const float4 B0 = *(const float4*)(nB + 8 * k8);
                const float4 B1 = *(const float4*)(nB + 8 * k8 + 4);
                BF8_STEP(wu, A0, A1, B0, B1)
            }
            #pragma unroll 4
            for (int k8 = 16; k8 < 24; ++k8) {
                const uint4 wu = w1b[k8 * LL + j];
                const float4 A0 = *(const float4*)(oA + 8 * k8 - 128);
                const float4 A1 = *(const float4*)(oA + 8 * k8 - 124);
                const float4 B0 = *(const float4*)(oB + 8 * k8 - 128);
                const float4 B1 = *(const float4*)(oB + 8 * k8 - 124);
                BF8_STEP(wu, A0, A1, B0, B1)
            }
        } else {
            #pragma unroll 4
            for (int k8 = 24; k8 < 32; ++k8) {
                const uint4 wu = w1b[k8 * LL + j];
                const float4 A0 = *(const float4*)(oA + 8 * k8 - 128);
                const float4 A1 = *(const float4*)(oA + 8 * k8 - 124);
                const float4 B0 = *(const float4*)(oB + 8 * k8 - 128);
                const float4 B1 = *(const float4*)(oB + 8 * k8 - 124);
                BF8_STEP(wu, A0, A1, B0, B1)
            }
            #pragma unroll 4
            for (int k8 = 32; k8 < 48; ++k8) {
                const uint4 wu = w1b[k8 * LL + j];
                const float4 A0 = *(const float4*)(dA + 8 * k8 - 256);
                const float4 A1 = *(const float4*)(dA + 8 * k8 - 252);
                const float4 B0 = *(const float4*)(dB + 8 * k8 - 256);
                const float4 B1 = *(const float4*)(dB + 8 * k8 - 252);
                BF8_STEP(wu, A0, A1, B0, B1)
            }
            {   // k8 = 48: k=384 is x; 385..391 zero-padded weights
                const uint4 wu = w1b[48 * LL + j];
                const float w0 = __uint_as_float(wu.x << 16);
                a0 = fmaf(w0, x[(size_t)eg0 * NN + node0], a0);
                a1 = fmaf(w0, x[(size_t)eg1 * NN + node1], a1);
            }
        }
        part1[g][0][j] = a0;
        part1[g][1][j] = a1;
    }
    __syncthreads();

    // Combine + bias + relu; thread (g,j) finishes edge e=g.
    h1s[g][j] = fmaxf(part1[0][g][j] + part1[1][g][j] + b1[j], 0.0f);
    __syncthreads();

    // Layer 2: g0 -> k8 [0,8), g1 -> [8,16)
    {
        const int k80 = g * 8, k81 = k80 + 8;
        float a0 = 0.f, a1 = 0.f;
        #pragma unroll 4
        for (int k8 = k80; k8 < k81; ++k8) {
            const uint4 wu = w2b[k8 * LL + j];
            const float4 A0 = *(const float4*)&h1s[0][8 * k8];
            const float4 A1 = *(const float4*)&h1s[0][8 * k8 + 4];
            const float4 B0 = *(const float4*)&h1s[1][8 * k8];
            const float4 B1 = *(const float4*)&h1s[1][8 * k8 + 4];
            BF8_STEP(wu, A0, A1, B0, B1)
        }
        part2[g][0][j] = a0;
        part2[g][1][j] = a1;
    }
    __syncthreads();

    // Final message; atomic segment-sum. Thread (g,j) finishes edge e=g.
    {
        const int node = g ? node1 : node0;
        const float m = part2[0][g][j] + part2[1][g][j] + b2[j];
        atomicAdd(ws + OFF_MSG + (size_t)node * LL + j, m);
    }
    if (tid < EPB) {
        const int node = tid ? node1 : node0;
        const float old = atomicAdd(ws + OFF_CNT + node, 1.0f);
        if (old == 0.0f) {
            const int pos = atomicAdd((int*)ws + OFF_COUNT, 1);
            ((int*)ws)[OFF_LIST + pos] = node;
        }
    }
}

// ---------------------------------------------------------------------------
// GRU over the compact seen list. r9 structure (GPB=4, 256 blocks, gate-split,
// raw-msg accumulate + end-scale), bf16 weights: 16 iters x 3 uint4 loads.
// ---------------------------------------------------------------------------
__global__ __launch_bounds__(256) void gru_kernel(
    const float* __restrict__ memory,
    const float* __restrict__ bih, const float* __restrict__ bhh,
    const float* __restrict__ ws, float* __restrict__ out)
{
    const int tid = threadIdx.x;
    const int g = tid >> 7, j = tid & 127;
    const int scount = ((const int*)ws)[OFF_COUNT];
    const int base = blockIdx.x * GPB;
    if (base >= scount) return;
    const int nact = min(GPB, scount - base);

    __shared__ float gates[6][GPB][LL];      // 12 KB
    __shared__ int   nodes_sh[GPB];

    int nd[GPB];
    #pragma unroll
    for (int s = 0; s < GPB; ++s)
        nd[s] = (base + s < scount) ? ((const int*)ws)[OFF_LIST + base + s]
                                    : ((const int*)ws)[OFF_LIST + base];
    if (tid < GPB) nodes_sh[tid] = nd[tid];

    const float* op[GPB];
    float rc[GPB] = {1.f, 1.f, 1.f, 1.f};
    #pragma unroll
    for (int s = 0; s < GPB; ++s) {
        if (g == 0) {
            op[s] = ws + OFF_MSG + (size_t)nd[s] * LL;
            rc[s] = 1.0f / ws[OFF_CNT + nd[s]];
        } else {
            op[s] = memory + (size_t)nd[s] * LL;
        }
    }

    const uint4* wpb = (const uint4*)(ws + (g ? OFF_WHHB : OFF_WIHB));
    float a0[GPB] = {}, a1[GPB] = {}, a2[GPB] = {};
    #pragma unroll 2
    for (int k8 = 0; k8 < NK8_2; ++k8) {
        const f8 w0 = unpack8(wpb[(0 * NK8_2 + k8) * LL + j]);
        const f8 w1 = unpack8(wpb[(1 * NK8_2 + k8) * LL + j]);
        const f8 w2 = unpack8(wpb[(2 * NK8_2 + k8) * LL + j]);
        #pragma unroll
        for (int s = 0; s < GPB; ++s) {
            const float4 v0 = *(const float4*)(op[s] + 8 * k8);
            const float4 v1 = *(const float4*)(op[s] + 8 * k8 + 4);
            const float v[8] = {v0.x, v0.y, v0.z, v0.w, v1.x, v1.y, v1.z, v1.w};
            #pragma unroll
            for (int c = 0; c < 8; ++c) {
                a0[s] = fmaf(w0.v[c], v[c], a0[s]);
                a1[s] = fmaf(w1.v[c], v[c], a1[s]);
                a2[s] = fmaf(w2.v[c], v[c], a2[s]);
            }
        }
    }
    #pragma unroll
    for (int s = 0; s < GPB; ++s) {
        gates[g * 3 + 0][s][j] = a0[s] * rc[s];
        gates[g * 3 + 1][s][j] = a1[s] * rc[s];
        gates[g * 3 + 2][s][j] = a2[s] * rc[s];
    }
    __syncthreads();

    // Finalize; h re-read coalesced from global (L2 hit).
    const int total = nact * LL;
    for (int o = tid; o < total; o += 256) {
        const int s = o >> 7, jj = o & 127;
        const int node = nodes_sh[s];
        const float ir = gates[0][s][jj] + bih[jj];
        const float iz = gates[1][s][jj] + bih[LL + jj];
        const float inn = gates[2][s][jj] + bih[2 * LL + jj];
        const float hr = gates[3][s][jj] + bhh[jj];
        const float hz = gates[4][s][jj] + bhh[LL + jj];
        const float hn = gates[5][s][jj] + bhh[2 * LL + jj];
        const float r = 1.0f / (1.0f + __expf(-(ir + hr)));
        const float z = 1.0f / (1.0f + __expf(-(iz + hz)));
        const float n = tanhf(inn + r * hn);
        const float h = memory[(size_t)node * LL + jj];
        out[(size_t)node * LL + jj] = (1.0f - z) * n + z * h;
    }
}

// ---------------------------------------------------------------------------
extern "C" void kernel_launch(void* const* d_in, const int* in_sizes, int n_in,
                              void* d_out, int out_size, void* d_ws, size_t ws_size,
                              hipStream_t stream) {
    const float* x        = (const float*)d_in[0];
    const float* memory   = (const float*)d_in[1];
    const float* delta_t  = (const float*)d_in[2];
    const float* src_w1   = (const float*)d_in[3];
    const float* src_b1   = (const float*)d_in[4];
    const float* src_w2   = (const float*)d_in[5];
    const float* src_b2   = (const float*)d_in[6];
    const float* tar_w1   = (const float*)d_in[7];
    const float* tar_b1   = (const float*)d_in[8];
    const float* tar_w2   = (const float*)d_in[9];
    const float* tar_b2   = (const float*)d_in[10];
    const float* gru_wih  = (const float*)d_in[11];
    const float* gru_whh  = (const float*)d_in[12];
    const float* gru_bih  = (const float*)d_in[13];
    const float* gru_bhh  = (const float*)d_in[14];
    const int*   source   = (const int*)d_in[15];
    const int*   target   = (const int*)d_in[16];

    float* out = (float*)d_out;
    float* ws  = (float*)d_ws;

    // 1) prep: zero accumulators + bf16-pack all weights
    prep_kernel<<<512, 256, 0, stream>>>(
        src_w1, tar_w1, src_w2, tar_w2, gru_wih, gru_whh, ws);

    // 2) edge messages (512 blocks, EPB=2) + memory->out copy (32 blocks)
    edge_msg_kernel<<<544, 256, 0, stream>>>(
        x, memory, delta_t, src_b1, src_b2, tar_b1, tar_b2,
        source, target, ws, out);

    // 3) GRU over compact seen list (256 blocks, GPB=4)
    gru_kernel<<<1024 / GPB, 256, 0, stream>>>(
        memory, gru_bih, gru_bhh, ws, out);
}

// Round 14
// 32.515 us; speedup vs baseline: 1.3362x; 1.0754x over previous
//
#include <hip/hip_runtime.h>
#include <math.h>

// Problem constants
#define BB 512      // batch (edges)
#define NN 4096     // nodes
#define LL 128      // feature dim
#define IN_DIM 385  // 3*L + ND
#define NK8_1 49    // ceil(IN_DIM/8) k-groups, layer 1 (8 bf16 per 16B load)
#define NK8_2 16    // LL/8 k-groups, layer 2 / GRU
#define EPB 2       // edges per block (edge kernel)
#define TASKS 1024  // 2*BB
#define GPB 4       // nodes per block (gru kernel)

// ---------------------------------------------------------------------------
// Workspace layout (float/int offsets; uint4 regions 16B-aligned)
// msgs/next need NO init (every slot written each call); head needs -1 fill.
// ---------------------------------------------------------------------------
#define OFF_MSGS  0                            // msgs[task][LL] f32 (dense)
#define OFF_HEAD  (OFF_MSGS + TASKS * LL)      // head[node] int (-1 init)
#define OFF_NEXT  (OFF_HEAD + NN)              // next[task] int
#define OFF_COUNT (OFF_NEXT + TASKS)           // seen_count (1 int) + pad
#define OFF_LIST  (OFF_COUNT + 4)              // seen list (1024 ints)
#define OFF_W1BS  (OFF_LIST + 1024)            // src w1 bf16 uint4[k8*128+j]
#define OFF_W1BT  (OFF_W1BS + NK8_1 * LL * 4)
#define OFF_W2BS  (OFF_W1BT + NK8_1 * LL * 4)
#define OFF_W2BT  (OFF_W2BS + NK8_2 * LL * 4)
#define OFF_WIHB  (OFF_W2BT + NK8_2 * LL * 4)  // uint4[(gate*16+k8)*128+j]
#define OFF_WHHB  (OFF_WIHB + 3 * NK8_2 * LL * 4)
// end ~ 1.01 MB

// ---------------------------------------------------------------------------
// bf16 helpers
// ---------------------------------------------------------------------------
__device__ inline unsigned short f2bf(float f) {          // RNE round
    unsigned u = __float_as_uint(f);
    return (unsigned short)((u + 0x7fffu + ((u >> 16) & 1u)) >> 16);
}
__device__ inline unsigned pack2(float lo, float hi) {
    return (unsigned)f2bf(lo) | ((unsigned)f2bf(hi) << 16);
}
struct f8 { float v[8]; };
__device__ inline f8 unpack8(uint4 u) {                   // 8 bf16 -> f32
    f8 r;
    r.v[0] = __uint_as_float(u.x << 16); r.v[1] = __uint_as_float(u.x & 0xffff0000u);
    r.v[2] = __uint_as_float(u.y << 16); r.v[3] = __uint_as_float(u.y & 0xffff0000u);
    r.v[4] = __uint_as_float(u.z << 16); r.v[5] = __uint_as_float(u.z & 0xffff0000u);
    r.v[6] = __uint_as_float(u.w << 16); r.v[7] = __uint_as_float(u.w & 0xffff0000u);
    return r;
}

// ---------------------------------------------------------------------------
// Prep: head[-1] fill (16 KB -- replaces the old 2.1 MB msg_sum zero) +
// bf16-pack all weights, lane-coalesced uint4[k8*128 + j].
// ---------------------------------------------------------------------------
__global__ __launch_bounds__(256) void prep_kernel(
    const float* __restrict__ sw1, const float* __restrict__ tw1,
    const float* __restrict__ sw2, const float* __restrict__ tw2,
    const float* __restrict__ wih, const float* __restrict__ whh,
    float* __restrict__ ws)
{
    const int i = blockIdx.x * 256 + threadIdx.x;
    const int stride = gridDim.x * 256;

    int* heads = (int*)ws + OFF_HEAD;
    for (int idx = i; idx < NN; idx += stride)
        heads[idx] = -1;
    if (i == 0)
        ((int*)ws)[OFF_COUNT] = 0;

    // layer-1: (L, IN=385) -> bf16x8 blocks, zero-padded to 392
    uint4* w1bs = (uint4*)(ws + OFF_W1BS);
    uint4* w1bt = (uint4*)(ws + OFF_W1BT);
    for (int idx = i; idx < NK8_1 * LL; idx += stride) {
        const int k8 = idx >> 7, j = idx & 127;
        const int k = k8 * 8;
        float a[8], b[8];
        #pragma unroll
        for (int c = 0; c < 8; ++c) {
            a[c] = (k + c < IN_DIM) ? sw1[j * IN_DIM + k + c] : 0.f;
            b[c] = (k + c < IN_DIM) ? tw1[j * IN_DIM + k + c] : 0.f;
        }
        w1bs[idx] = make_uint4(pack2(a[0], a[1]), pack2(a[2], a[3]),
                               pack2(a[4], a[5]), pack2(a[6], a[7]));
        w1bt[idx] = make_uint4(pack2(b[0], b[1]), pack2(b[2], b[3]),
                               pack2(b[4], b[5]), pack2(b[6], b[7]));
    }
    // layer-2: (L, L)
    uint4* w2bs = (uint4*)(ws + OFF_W2BS);
    uint4* w2bt = (uint4*)(ws + OFF_W2BT);
    for (int idx = i; idx < NK8_2 * LL; idx += stride) {
        const int k8 = idx >> 7, j = idx & 127;
        const int k = k8 * 8;
        const float* pa = sw2 + j * LL + k;
        const float* pb = tw2 + j * LL + k;
        w2bs[idx] = make_uint4(pack2(pa[0], pa[1]), pack2(pa[2], pa[3]),
                               pack2(pa[4], pa[5]), pack2(pa[6], pa[7]));
        w2bt[idx] = make_uint4(pack2(pb[0], pb[1]), pack2(pb[2], pb[3]),
                               pack2(pb[4], pb[5]), pack2(pb[6], pb[7]));
    }
    // GRU: (3L, L) -> uint4[(gate*16 + k8)*L + j]
    uint4* wihb = (uint4*)(ws + OFF_WIHB);
    uint4* whhb = (uint4*)(ws + OFF_WHHB);
    for (int idx = i; idx < 3 * NK8_2 * LL; idx += stride) {
        const int j = idx & 127;
        const int gk = idx >> 7;             // gate*16 + k8
        const int gate = gk >> 4, k8 = gk & 15;
        const float* pa = wih + (gate * LL + j) * LL + k8 * 8;
        const float* pb = whh + (gate * LL + j) * LL + k8 * 8;
        wihb[idx] = make_uint4(pack2(pa[0], pa[1]), pack2(pa[2], pa[3]),
                               pack2(pa[4], pa[5]), pack2(pa[6], pa[7]));
        whhb[idx] = make_uint4(pack2(pb[0], pb[1]), pack2(pb[2], pb[3]),
                               pack2(pb[4], pb[5]), pack2(pb[6], pb[7]));
    }
}

// One bf16x8 weight block against two edges' 8 input floats.
#define BF8_STEP(WU, A0, A1, B0, B1) {                                  \
    const f8 W_ = unpack8(WU);                                          \
    a0 = fmaf(W_.v[0], (A0).x, a0); a1 = fmaf(W_.v[0], (B0).x, a1);     \
    a0 = fmaf(W_.v[1], (A0).y, a0); a1 = fmaf(W_.v[1], (B0).y, a1);     \
    a0 = fmaf(W_.v[2], (A0).z, a0); a1 = fmaf(W_.v[2], (B0).z, a1);     \
    a0 = fmaf(W_.v[3], (A0).w, a0); a1 = fmaf(W_.v[3], (B0).w, a1);     \
    a0 = fmaf(W_.v[4], (A1).x, a0); a1 = fmaf(W_.v[4], (B1).x, a1);     \
    a0 = fmaf(W_.v[5], (A1).y, a0); a1 = fmaf(W_.v[5], (B1).y, a1);     \
    a0 = fmaf(W_.v[6], (A1).z, a0); a1 = fmaf(W_.v[6], (B1).z, a1);     \
    a0 = fmaf(W_.v[7], (A1).w, a0); a1 = fmaf(W_.v[7], (B1).w, a1); }

// ---------------------------------------------------------------------------
// Edge messages: r13 bf16 body; output is a DENSE non-atomic message write +
// one atomicExch chain-link per task (no 128-lane atomicAdds, no zeroed
// accumulator). Blocks >= 512: memory->out passthrough copy.
// ---------------------------------------------------------------------------
__global__ __launch_bounds__(256) void edge_msg_kernel(
    const float* __restrict__ x,        // (B, N, 1)
    const float* __restrict__ memory,   // (N, L)
    const float* __restrict__ delta_t,  // (B, N, L)
    const float* __restrict__ sb1, const float* __restrict__ sb2,
    const float* __restrict__ tb1, const float* __restrict__ tb2,
    const int* __restrict__ source, const int* __restrict__ target,
    float* __restrict__ ws, float* __restrict__ out)
{
    const int tid = threadIdx.x;

    // ---- copy blocks ----
    if (blockIdx.x >= 512) {
        const int cb = blockIdx.x - 512;
        float4* out4 = (float4*)out;
        const float4* mem4 = (const float4*)memory;
        for (int idx = cb * 256 + tid; idx < NN * LL / 4; idx += 32 * 256)
            out4[idx] = mem4[idx];
        return;
    }

    // ---- edge blocks ----
    const int side  = blockIdx.x & 1;
    const int chunk = blockIdx.x >> 1;
    const int g     = tid >> 7;              // k-split group
    const int j     = tid & 127;             // output feature

    const int eg0 = chunk * EPB, eg1 = eg0 + 1;
    const int s0 = source[eg0], t0 = target[eg0];
    const int s1 = source[eg1], t1 = target[eg1];
    const int node0  = side ? t0 : s0, other0 = side ? s0 : t0;
    const int node1  = side ? t1 : s1, other1 = side ? s1 : t1;

    __shared__ float h1s[EPB][LL];
    __shared__ float part1[2][EPB][LL];
    __shared__ float part2[2][EPB][LL];

    const uint4* w1b = (const uint4*)(ws + (side ? OFF_W1BT : OFF_W1BS));
    const uint4* w2b = (const uint4*)(ws + (side ? OFF_W2BT : OFF_W2BS));
    const float* b1  = side ? tb1 : sb1;
    const float* b2  = side ? tb2 : sb2;

    // Layer 1, k8 segments: [0,16)=mem[node], [16,32)=mem[other],
    // [32,48)=delta_t, 48=x. Split g0 [0,24), g1 [24,49).
    {
        float a0 = 0.f, a1 = 0.f;
        const float* nA = memory + (size_t)node0 * LL;
        const float* nB = memory + (size_t)node1 * LL;
        const float* oA = memory + (size_t)other0 * LL;
        const float* oB = memory + (size_t)other1 * LL;
        const float* dA = delta_t + ((size_t)eg0 * NN + node0) * LL;
        const float* dB = delta_t + ((size_t)eg1 * NN + node1) * LL;

        if (g == 0) {
            #pragma unroll 4
            for (int k8 = 0; k8 < 16; ++k8) {
                const uint4 wu = w1b[k8 * LL + j];
                const float4 A0 = *(const float4*)(nA + 8 * k8);
                const float4 A1 = *(const float4*)(nA + 8 * k8 + 4);
                const float4 B0 = *(const float4*)(nB + 8 * k8);
                const float4 B1 = *(const float4*)(nB + 8 * k8 + 4);
                BF8_STEP(wu, A0, A1, B0, B1)
            }
            #pragma unroll 4
            for (int k8 = 16; k8 < 24; ++k8) {
                const uint4 wu = w1b[k8 * LL + j];
                const float4 A0 = *(const float4*)(oA + 8 * k8 - 128);
                const float4 A1 = *(const float4*)(oA + 8 * k8 - 124);
                const float4 B0 = *(const float4*)(oB + 8 * k8 - 128);
                const float4 B1 = *(const float4*)(oB + 8 * k8 - 124);
                BF8_STEP(wu, A0, A1, B0, B1)
            }
        } else {
            #pragma unroll 4
            for (int k8 = 24; k8 < 32; ++k8) {
                const uint4 wu = w1b[k8 * LL + j];
                const float4 A0 = *(const float4*)(oA + 8 * k8 - 128);
                const float4 A1 = *(const float4*)(oA + 8 * k8 - 124);
                const float4 B0 = *(const float4*)(oB + 8 * k8 - 128);
                const float4 B1 = *(const float4*)(oB + 8 * k8 - 124);
                BF8_STEP(wu, A0, A1, B0, B1)
            }
            #pragma unroll 4
            for (int k8 = 32; k8 < 48; ++k8) {
                const uint4 wu = w1b[k8 * LL + j];
                const float4 A0 = *(const float4*)(dA + 8 * k8 - 256);
                const float4 A1 = *(const float4*)(dA + 8 * k8 - 252);
                const float4 B0 = *(const float4*)(dB + 8 * k8 - 256);
                const float4 B1 = *(const float4*)(dB + 8 * k8 - 252);
                BF8_STEP(wu, A0, A1, B0, B1)
            }
            {   // k8 = 48: k=384 is x; 385..391 zero-padded weights
                const uint4 wu = w1b[48 * LL + j];
                const float w0 = __uint_as_float(wu.x << 16);
                a0 = fmaf(w0, x[(size_t)eg0 * NN + node0], a0);
                a1 = fmaf(w0, x[(size_t)eg1 * NN + node1], a1);
            }
        }
        part1[g][0][j] = a0;
        part1[g][1][j] = a1;
    }
    __syncthreads();

    // Combine + bias + relu; thread (g,j) finishes edge e=g.
    h1s[g][j] = fmaxf(part1[0][g][j] + part1[1][g][j] + b1[j], 0.0f);
    __syncthreads();

    // Layer 2: g0 -> k8 [0,8), g1 -> [8,16)
    {
        const int k80 = g * 8, k81 = k80 + 8;
        float a0 = 0.f, a1 = 0.f;
        #pragma unroll 4
        for (int k8 = k80; k8 < k81; ++k8) {
            const uint4 wu = w2b[k8 * LL + j];
            const float4 A0 = *(const float4*)&h1s[0][8 * k8];
            const float4 A1 = *(const float4*)&h1s[0][8 * k8 + 4];
            const float4 B0 = *(const float4*)&h1s[1][8 * k8];
            const float4 B1 = *(const float4*)&h1s[1][8 * k8 + 4];
            BF8_STEP(wu, A0, A1, B0, B1)
        }
        part2[g][0][j] = a0;
        part2[g][1][j] = a1;
    }
    __syncthreads();

    // DENSE message write (no atomics); thread (g,j) finishes edge e=g.
    {
        const int task = side * BB + (g ? eg1 : eg0);
        const float m = part2[0][g][j] + part2[1][g][j] + b2[j];
        ws[OFF_MSGS + (size_t)task * LL + j] = m;
    }
    // Chain-link + first-toucher compaction (one exch per task).
    if (tid < EPB) {
        const int node = tid ? node1 : node0;
        const int task = side * BB + (tid ? eg1 : eg0);
        const int old = atomicExch((int*)ws + OFF_HEAD + node, task);
        ((int*)ws)[OFF_NEXT + task] = old;
        if (old == -1) {
            const int pos = atomicAdd((int*)ws + OFF_COUNT, 1);
            ((int*)ws)[OFF_LIST + pos] = node;
        }
    }
}

// ---------------------------------------------------------------------------
// GRU over the compact seen list. GPB=4 nodes/block, 256 blocks, gate-split.
// g0 aggregates each slot's chain (avg length ~1.2) into LDS agg rows;
// g1 stages h rows. bf16 packed weights, matvec reads LDS broadcast rows.
// ---------------------------------------------------------------------------
__global__ __launch_bounds__(256) void gru_kernel(
    const float* __restrict__ memory,
    const float* __restrict__ bih, const float* __restrict__ bhh,
    const float* __restrict__ ws, float* __restrict__ out)
{
    const int tid = threadIdx.x;
    const int g = tid >> 7, j = tid & 127;
    const int scount = ((const int*)ws)[OFF_COUNT];
    const int base = blockIdx.x * GPB;
    if (base >= scount) return;
    const int nact = min(GPB, scount - base);

    __shared__ float ah[2 * GPB][LL];        // [slot]=agg rows, [GPB+slot]=h
    __shared__ float gates[6][GPB][LL];      // 12 KB
    __shared__ int   nodes_sh[GPB];

    const int* heads = (const int*)ws + OFF_HEAD;
    const int* nexts = (const int*)ws + OFF_NEXT;

    int nd[GPB];
    #pragma unroll
    for (int s = 0; s < GPB; ++s)
        nd[s] = (base + s < scount) ? ((const int*)ws)[OFF_LIST + base + s]
                                    : ((const int*)ws)[OFF_LIST + base];
    if (tid < GPB) nodes_sh[tid] = nd[tid];

    // Stage operands: g0 walks chains -> agg; g1 loads h rows.
    if (g == 0) {
        #pragma unroll
        for (int s = 0; s < GPB; ++s) {
            float acc = 0.0f;
            int c = 0;
            for (int t = heads[nd[s]]; t != -1; t = nexts[t]) {
                acc += ws[OFF_MSGS + (size_t)t * LL + j];
                ++c;
            }
            ah[s][j] = acc / (float)c;       // c >= 1 (listed node)
        }
    } else {
        #pragma unroll
        for (int s = 0; s < GPB; ++s)
            ah[GPB + s][j] = memory[(size_t)nd[s] * LL + j];
    }
    __syncthreads();

    // Gate-split matvec: g0 -> wih vs agg, g1 -> whh vs h (LDS rows).
    const uint4* wpb = (const uint4*)(ws + (g ? OFF_WHHB : OFF_WIHB));
    float a0[GPB] = {}, a1[GPB] = {}, a2[GPB] = {};
    #pragma unroll 2
    for (int k8 = 0; k8 < NK8_2; ++k8) {
        const f8 w0 = unpack8(wpb[(0 * NK8_2 + k8) * LL + j]);
        const f8 w1 = unpack8(wpb[(1 * NK8_2 + k8) * LL + j]);
        const f8 w2 = unpack8(wpb[(2 * NK8_2 + k8) * LL + j]);
        #pragma unroll
        for (int s = 0; s < GPB; ++s) {
            const float4 v0 = *(const float4*)&ah[g * GPB + s][8 * k8];
            const float4 v1 = *(const float4*)&ah[g * GPB + s][8 * k8 + 4];
            const float v[8] = {v0.x, v0.y, v0.z, v0.w, v1.x, v1.y, v1.z, v1.w};
            #pragma unroll
            for (int c = 0; c < 8; ++c) {
                a0[s] = fmaf(w0.v[c], v[c], a0[s]);
                a1[s] = fmaf(w1.v[c], v[c], a1[s]);
                a2[s] = fmaf(w2.v[c], v[c], a2[s]);
            }
        }
    }
    #pragma unroll
    for (int s = 0; s < GPB; ++s) {
        gates[g * 3 + 0][s][j] = a0[s];
        gates[g * 3 + 1][s][j] = a1[s];
        gates[g * 3 + 2][s][j] = a2[s];
    }
    __syncthreads();

    // Finalize; h from LDS.
    const int total = nact * LL;
    for (int o = tid; o < total; o += 256) {
        const int s = o >> 7, jj = o & 127;
        const int node = nodes_sh[s];
        const float ir = gates[0][s][jj] + bih[jj];
        const float iz = gates[1][s][jj] + bih[LL + jj];
        const float inn = gates[2][s][jj] + bih[2 * LL + jj];
        const float hr = gates[3][s][jj] + bhh[jj];
        const float hz = gates[4][s][jj] + bhh[LL + jj];
        const float hn = gates[5][s][jj] + bhh[2 * LL + jj];
        const float r = 1.0f / (1.0f + __expf(-(ir + hr)));
        const float z = 1.0f / (1.0f + __expf(-(iz + hz)));
        const float n = tanhf(inn + r * hn);
        const float h = ah[GPB + s][jj];
        out[(size_t)node * LL + jj] = (1.0f - z) * n + z * h;
    }
}

// ---------------------------------------------------------------------------
extern "C" void kernel_launch(void* const* d_in, const int* in_sizes, int n_in,
                              void* d_out, int out_size, void* d_ws, size_t ws_size,
                              hipStream_t stream) {
    const float* x        = (const float*)d_in[0];
    const float* memory   = (const float*)d_in[1];
    const float* delta_t  = (const float*)d_in[2];
    const float* src_w1   = (const float*)d_in[3];
    const float* src_b1   = (const float*)d_in[4];
    const float* src_w2   = (const float*)d_in[5];
    const float* src_b2   = (const float*)d_in[6];
    const float* tar_w1   = (const float*)d_in[7];
    const float* tar_b1   = (const float*)d_in[8];
    const float* tar_w2   = (const float*)d_in[9];
    const float* tar_b2   = (const float*)d_in[10];
    const float* gru_wih  = (const float*)d_in[11];
    const float* gru_whh  = (const float*)d_in[12];
    const float* gru_bih  = (const float*)d_in[13];
    const float* gru_bhh  = (const float*)d_in[14];
    const int*   source   = (const int*)d_in[15];
    const int*   target   = (const int*)d_in[16];

    float* out = (float*)d_out;
    float* ws  = (float*)d_ws;

    // 1) prep: head[-1] fill + bf16-pack all weights (no 2MB zeroing)
    prep_kernel<<<256, 256, 0, stream>>>(
        src_w1, tar_w1, src_w2, tar_w2, gru_wih, gru_whh, ws);

    // 2) edge messages (512 blocks, EPB=2) + memory->out copy (32 blocks)
    edge_msg_kernel<<<544, 256, 0, stream>>>(
        x, memory, delta_t, src_b1, src_b2, tar_b1, tar_b2,
        source, target, ws, out);

    // 3) GRU over compact seen list (256 blocks, GPB=4, chain aggregation)
    gru_kernel<<<1024 / GPB, 256, 0, stream>>>(
        memory, gru_bih, gru_bhh, ws, out);
}

// Round 15
// 30.645 us; speedup vs baseline: 1.4177x; 1.0610x over previous
//
#include <hip/hip_runtime.h>
#include <math.h>

// Problem constants
#define BB 512      // batch (edges)
#define NN 4096     // nodes
#define LL 128      // feature dim
#define IN_DIM 385  // 3*L + ND
#define NK8_1 49    // ceil(IN_DIM/8) k-groups, layer 1 (8 bf16 per 16B load)
#define NK8_2 16    // LL/8 k-groups, layer 2 / GRU
#define EPB 4       // edges per block (edge kernel)
#define TASKS 1024  // 2*BB
#define GPB 4       // nodes per block (gru kernel)

// ---------------------------------------------------------------------------
// Workspace layout (float/int offsets; uint4 regions 16B-aligned)
// ---------------------------------------------------------------------------
#define OFF_MSGS  0                            // msgs[task][LL] f32 (dense)
#define OFF_HEAD  (OFF_MSGS + TASKS * LL)      // head[node] int (-1 init)
#define OFF_NEXT  (OFF_HEAD + NN)              // next[task] int
#define OFF_COUNT (OFF_NEXT + TASKS)           // seen_count (1 int) + pad
#define OFF_LIST  (OFF_COUNT + 4)              // seen list (1024 ints)
#define OFF_W1BS  (OFF_LIST + 1024)            // src w1 bf16 uint4[k8*128+j]
#define OFF_W1BT  (OFF_W1BS + NK8_1 * LL * 4)
#define OFF_W2BS  (OFF_W1BT + NK8_1 * LL * 4)
#define OFF_W2BT  (OFF_W2BS + NK8_2 * LL * 4)
#define OFF_WIHB  (OFF_W2BT + NK8_2 * LL * 4)  // uint4[(gate*16+k8)*128+j]
#define OFF_WHHB  (OFF_WIHB + 3 * NK8_2 * LL * 4)

// ---------------------------------------------------------------------------
// bf16 helpers
// ---------------------------------------------------------------------------
__device__ inline unsigned short f2bf(float f) {          // RNE round
    unsigned u = __float_as_uint(f);
    return (unsigned short)((u + 0x7fffu + ((u >> 16) & 1u)) >> 16);
}
__device__ inline unsigned pack2(float lo, float hi) {
    return (unsigned)f2bf(lo) | ((unsigned)f2bf(hi) << 16);
}
struct f8 { float v[8]; };
__device__ inline f8 unpack8(uint4 u) {                   // 8 bf16 -> f32
    f8 r;
    r.v[0] = __uint_as_float(u.x << 16); r.v[1] = __uint_as_float(u.x & 0xffff0000u);
    r.v[2] = __uint_as_float(u.y << 16); r.v[3] = __uint_as_float(u.y & 0xffff0000u);
    r.v[4] = __uint_as_float(u.z << 16); r.v[5] = __uint_as_float(u.z & 0xffff0000u);
    r.v[6] = __uint_as_float(u.w << 16); r.v[7] = __uint_as_float(u.w & 0xffff0000u);
    return r;
}

// ---------------------------------------------------------------------------
// Prep (minimal critical path): head[-1] fill + bf16-pack w1 and w2 only.
// GRU weight pack moved to edge kernel's extra blocks (consumed in kernel 3).
// ---------------------------------------------------------------------------
__global__ __launch_bounds__(256) void prep_kernel(
    const float* __restrict__ sw1, const float* __restrict__ tw1,
    const float* __restrict__ sw2, const float* __restrict__ tw2,
    float* __restrict__ ws)
{
    const int i = blockIdx.x * 256 + threadIdx.x;
    const int stride = gridDim.x * 256;

    int* heads = (int*)ws + OFF_HEAD;
    for (int idx = i; idx < NN; idx += stride)
        heads[idx] = -1;
    if (i == 0)
        ((int*)ws)[OFF_COUNT] = 0;

    // layer-1: (L, IN=385) -> bf16x8 blocks, zero-padded to 392
    uint4* w1bs = (uint4*)(ws + OFF_W1BS);
    uint4* w1bt = (uint4*)(ws + OFF_W1BT);
    for (int idx = i; idx < NK8_1 * LL; idx += stride) {
        const int k8 = idx >> 7, j = idx & 127;
        const int k = k8 * 8;
        float a[8], b[8];
        #pragma unroll
        for (int c = 0; c < 8; ++c) {
            a[c] = (k + c < IN_DIM) ? sw1[j * IN_DIM + k + c] : 0.f;
            b[c] = (k + c < IN_DIM) ? tw1[j * IN_DIM + k + c] : 0.f;
        }
        w1bs[idx] = make_uint4(pack2(a[0], a[1]), pack2(a[2], a[3]),
                               pack2(a[4], a[5]), pack2(a[6], a[7]));
        w1bt[idx] = make_uint4(pack2(b[0], b[1]), pack2(b[2], b[3]),
                               pack2(b[4], b[5]), pack2(b[6], b[7]));
    }
    // layer-2: (L, L)
    uint4* w2bs = (uint4*)(ws + OFF_W2BS);
    uint4* w2bt = (uint4*)(ws + OFF_W2BT);
    for (int idx = i; idx < NK8_2 * LL; idx += stride) {
        const int k8 = idx >> 7, j = idx & 127;
        const int k = k8 * 8;
        const float* pa = sw2 + j * LL + k;
        const float* pb = tw2 + j * LL + k;
        w2bs[idx] = make_uint4(pack2(pa[0], pa[1]), pack2(pa[2], pa[3]),
                               pack2(pa[4], pa[5]), pack2(pa[6], pa[7]));
        w2bt[idx] = make_uint4(pack2(pb[0], pb[1]), pack2(pb[2], pb[3]),
                               pack2(pb[4], pb[5]), pack2(pb[6], pb[7]));
    }
}

// One bf16x8 weight block against FOUR edges' 8 input floats each.
#define BF8_STEP4(WU, P0, P1, P2, P3, OFS) {                            \
    const f8 W_ = unpack8(WU);                                          \
    const float4 A0 = *(const float4*)((P0) + (OFS));                   \
    const float4 A1 = *(const float4*)((P0) + (OFS) + 4);               \
    const float4 B0 = *(const float4*)((P1) + (OFS));                   \
    const float4 B1 = *(const float4*)((P1) + (OFS) + 4);               \
    const float4 C0 = *(const float4*)((P2) + (OFS));                   \
    const float4 C1 = *(const float4*)((P2) + (OFS) + 4);               \
    const float4 D0 = *(const float4*)((P3) + (OFS));                   \
    const float4 D1 = *(const float4*)((P3) + (OFS) + 4);               \
    a0 = fmaf(W_.v[0], A0.x, a0); a1 = fmaf(W_.v[0], B0.x, a1);         \
    a2 = fmaf(W_.v[0], C0.x, a2); a3 = fmaf(W_.v[0], D0.x, a3);         \
    a0 = fmaf(W_.v[1], A0.y, a0); a1 = fmaf(W_.v[1], B0.y, a1);         \
    a2 = fmaf(W_.v[1], C0.y, a2); a3 = fmaf(W_.v[1], D0.y, a3);         \
    a0 = fmaf(W_.v[2], A0.z, a0); a1 = fmaf(W_.v[2], B0.z, a1);         \
    a2 = fmaf(W_.v[2], C0.z, a2); a3 = fmaf(W_.v[2], D0.z, a3);         \
    a0 = fmaf(W_.v[3], A0.w, a0); a1 = fmaf(W_.v[3], B0.w, a1);         \
    a2 = fmaf(W_.v[3], C0.w, a2); a3 = fmaf(W_.v[3], D0.w, a3);         \
    a0 = fmaf(W_.v[4], A1.x, a0); a1 = fmaf(W_.v[4], B1.x, a1);         \
    a2 = fmaf(W_.v[4], C1.x, a2); a3 = fmaf(W_.v[4], D1.x, a3);         \
    a0 = fmaf(W_.v[5], A1.y, a0); a1 = fmaf(W_.v[5], B1.y, a1);         \
    a2 = fmaf(W_.v[5], C1.y, a2); a3 = fmaf(W_.v[5], D1.y, a3);         \
    a0 = fmaf(W_.v[6], A1.z, a0); a1 = fmaf(W_.v[6], B1.z, a1);         \
    a2 = fmaf(W_.v[6], C1.z, a2); a3 = fmaf(W_.v[6], D1.z, a3);         \
    a0 = fmaf(W_.v[7], A1.w, a0); a1 = fmaf(W_.v[7], B1.w, a1);         \
    a2 = fmaf(W_.v[7], C1.w, a2); a3 = fmaf(W_.v[7], D1.w, a3); }

// ---------------------------------------------------------------------------
// Edge messages: EPB=4, 512 threads (4 k-groups x 128 features). 256 edge
// blocks (8 waves/CU) -- HALF the weight traffic of EPB=2 at equal waves.
// Blocks 256..271: memory->out copy. Blocks 272..295: GRU weight bf16-pack.
// ---------------------------------------------------------------------------
__global__ __launch_bounds__(512) void edge_msg_kernel(
    const float* __restrict__ x,        // (B, N, 1)
    const float* __restrict__ memory,   // (N, L)
    const float* __restrict__ delta_t,  // (B, N, L)
    const float* __restrict__ sb1, const float* __restrict__ sb2,
    const float* __restrict__ tb1, const float* __restrict__ tb2,
    const float* __restrict__ wih, const float* __restrict__ whh,
    const int* __restrict__ source, const int* __restrict__ target,
    float* __restrict__ ws, float* __restrict__ out)
{
    const int tid = threadIdx.x;

    if (blockIdx.x >= 256) {
        if (blockIdx.x < 272) {
            // ---- copy blocks (16 x 512) ----
            const int cb = blockIdx.x - 256;
            float4* out4 = (float4*)out;
            const float4* mem4 = (const float4*)memory;
            for (int idx = cb * 512 + tid; idx < NN * LL / 4; idx += 16 * 512)
                out4[idx] = mem4[idx];
        } else {
            // ---- GRU weight bf16-pack (24 x 512 = 12288 = 2*3*16*128) ----
            const int idx = (blockIdx.x - 272) * 512 + tid;  // [0, 12288)
            const int half = idx >= 6144;                    // 0: wih, 1: whh
            const int id2 = idx - half * 6144;
            const int j = id2 & 127;
            const int gk = id2 >> 7;             // gate*16 + k8
            const int gate = gk >> 4, k8 = gk & 15;
            const float* p = (half ? whh : wih) + (gate * LL + j) * LL + k8 * 8;
            uint4* dst = (uint4*)(ws + (half ? OFF_WHHB : OFF_WIHB));
            dst[id2] = make_uint4(pack2(p[0], p[1]), pack2(p[2], p[3]),
                                  pack2(p[4], p[5]), pack2(p[6], p[7]));
        }
        return;
    }

    // ---- edge blocks: 4 edges, one side ----
    const int side  = blockIdx.x & 1;
    const int chunk = blockIdx.x >> 1;       // 0..127
    const int g     = tid >> 7;              // k-split group 0..3
    const int j     = tid & 127;             // output feature

    int eg[EPB], nodev[EPB], otherv[EPB];
    #pragma unroll
    for (int e = 0; e < EPB; ++e) {
        eg[e] = chunk * EPB + e;
        const int s = source[eg[e]], t = target[eg[e]];
        nodev[e]  = side ? t : s;
        otherv[e] = side ? s : t;
    }

    __shared__ float h1s[EPB][LL];
    __shared__ float part1[4][EPB][LL];
    __shared__ float part2[4][EPB][LL];

    const uint4* w1b = (const uint4*)(ws + (side ? OFF_W1BT : OFF_W1BS));
    const uint4* w2b = (const uint4*)(ws + (side ? OFF_W2BT : OFF_W2BS));
    const float* b1  = side ? tb1 : sb1;
    const float* b2  = side ? tb2 : sb2;

    const float* n0 = memory + (size_t)nodev[0] * LL;
    const float* n1 = memory + (size_t)nodev[1] * LL;
    const float* n2 = memory + (size_t)nodev[2] * LL;
    const float* n3 = memory + (size_t)nodev[3] * LL;
    const float* o0 = memory + (size_t)otherv[0] * LL;
    const float* o1 = memory + (size_t)otherv[1] * LL;
    const float* o2 = memory + (size_t)otherv[2] * LL;
    const float* o3 = memory + (size_t)otherv[3] * LL;
    const float* d0 = delta_t + ((size_t)eg[0] * NN + nodev[0]) * LL;
    const float* d1 = delta_t + ((size_t)eg[1] * NN + nodev[1]) * LL;
    const float* d2 = delta_t + ((size_t)eg[2] * NN + nodev[2]) * LL;
    const float* d3 = delta_t + ((size_t)eg[3] * NN + nodev[3]) * LL;

    // Layer 1, k8 segments: [0,16)=mem[node], [16,32)=mem[other],
    // [32,48)=delta_t, 48=x. Groups: g0 [0,12), g1 [12,24), g2 [24,36),
    // g3 [36,49) -- 12/12/12/13.
    {
        float a0 = 0.f, a1 = 0.f, a2 = 0.f, a3 = 0.f;
        if (g == 0) {
            #pragma unroll 4
            for (int k8 = 0; k8 < 12; ++k8) {
                const uint4 wu = w1b[k8 * LL + j];
                BF8_STEP4(wu, n0, n1, n2, n3, 8 * k8)
            }
        } else if (g == 1) {
            #pragma unroll 4
            for (int k8 = 12; k8 < 16; ++k8) {
                const uint4 wu = w1b[k8 * LL + j];
                BF8_STEP4(wu, n0, n1, n2, n3, 8 * k8)
            }
            #pragma unroll 4
            for (int k8 = 16; k8 < 24; ++k8) {
                const uint4 wu = w1b[k8 * LL + j];
                BF8_STEP4(wu, o0, o1, o2, o3, 8 * k8 - 128)
            }
        } else if (g == 2) {
            #pragma unroll 4
            for (int k8 = 24; k8 < 32; ++k8) {
                const uint4 wu = w1b[k8 * LL + j];
                BF8_STEP4(wu, o0, o1, o2, o3, 8 * k8 - 128)
            }
            #pragma unroll 4
            for (int k8 = 32; k8 < 36; ++k8) {
                const uint4 wu = w1b[k8 * LL + j];
                BF8_STEP4(wu, d0, d1, d2, d3, 8 * k8 - 256)
            }
        } else {
            #pragma unroll 4
            for (int k8 = 36; k8 < 48; ++k8) {
                const uint4 wu = w1b[k8 * LL + j];
                BF8_STEP4(wu, d0, d1, d2, d3, 8 * k8 - 256)
            }
            {   // k8 = 48: k=384 is x; 385..391 zero-padded weights
                const uint4 wu = w1b[48 * LL + j];
                const float w0 = __uint_as_float(wu.x << 16);
                a0 = fmaf(w0, x[(size_t)eg[0] * NN + nodev[0]], a0);
                a1 = fmaf(w0, x[(size_t)eg[1] * NN + nodev[1]], a1);
                a2 = fmaf(w0, x[(size_t)eg[2] * NN + nodev[2]], a2);
                a3 = fmaf(w0, x[(size_t)eg[3] * NN + nodev[3]], a3);
            }
        }
        part1[g][0][j] = a0; part1[g][1][j] = a1;
        part1[g][2][j] = a2; part1[g][3][j] = a3;
    }
    __syncthreads();

    // Combine + bias + relu; group g finishes edge e=g.
    h1s[g][j] = fmaxf(part1[0][g][j] + part1[1][g][j]
                    + part1[2][g][j] + part1[3][g][j] + b1[j], 0.0f);
    __syncthreads();

    // Layer 2: group g -> k8 [4g, 4g+4)
    {
        const int k80 = g * 4, k81 = k80 + 4;
        float a0 = 0.f, a1 = 0.f, a2 = 0.f, a3 = 0.f;
        #pragma unroll 4
        for (int k8 = k80; k8 < k81; ++k8) {
            const uint4 wu = w2b[k8 * LL + j];
            BF8_STEP4(wu, &h1s[0][0], &h1s[1][0], &h1s[2][0], &h1s[3][0], 8 * k8)
        }
        part2[g][0][j] = a0; part2[g][1][j] = a1;
        part2[g][2][j] = a2; part2[g][3][j] = a3;
    }
    __syncthreads();

    // DENSE message write; group g finishes edge e=g.
    {
        const int task = side * BB + eg[g];
        const float m = part2[0][g][j] + part2[1][g][j]
                      + part2[2][g][j] + part2[3][g][j] + b2[j];
        ws[OFF_MSGS + (size_t)task * LL + j] = m;
    }
    // Chain-link + first-toucher compaction (one exch per task).
    if (tid < EPB) {
        const int node = nodev[tid];
        const int task = side * BB + eg[tid];
        const int old = atomicExch((int*)ws + OFF_HEAD + node, task);
        ((int*)ws)[OFF_NEXT + task] = old;
        if (old == -1) {
            const int pos = atomicAdd((int*)ws + OFF_COUNT, 1);
            ((int*)ws)[OFF_LIST + pos] = node;
        }
    }
}

// ---------------------------------------------------------------------------
// GRU over the compact seen list (r14-proven). GPB=4, 256 blocks, gate-split;
// chain aggregation; bf16 packed weights.
// ---------------------------------------------------------------------------
__global__ __launch_bounds__(256) void gru_kernel(
    const float* __restrict__ memory,
    const float* __restrict__ bih, const float* __restrict__ bhh,
    const float* __restrict__ ws, float* __restrict__ out)
{
    const int tid = threadIdx.x;
    const int g = tid >> 7, j = tid & 127;
    const int scount = ((const int*)ws)[OFF_COUNT];
    const int base = blockIdx.x * GPB;
    if (base >= scount) return;
    const int nact = min(GPB, scount - base);

    __shared__ float ah[2 * GPB][LL];        // [slot]=agg rows, [GPB+slot]=h
    __shared__ float gates[6][GPB][LL];      // 12 KB
    __shared__ int   nodes_sh[GPB];

    const int* heads = (const int*)ws + OFF_HEAD;
    const int* nexts = (const int*)ws + OFF_NEXT;

    int nd[GPB];
    #pragma unroll
    for (int s = 0; s < GPB; ++s)
        nd[s] = (base + s < scount) ? ((const int*)ws)[OFF_LIST + base + s]
                                    : ((const int*)ws)[OFF_LIST + base];
    if (tid < GPB) nodes_sh[tid] = nd[tid];

    // Stage operands: g0 walks chains -> agg; g1 loads h rows.
    if (g == 0) {
        #pragma unroll
        for (int s = 0; s < GPB; ++s) {
            float acc = 0.0f;
            int c = 0;
            for (int t = heads[nd[s]]; t != -1; t = nexts[t]) {
                acc += ws[OFF_MSGS + (size_t)t * LL + j];
                ++c;
            }
            ah[s][j] = acc / (float)c;       // c >= 1 (listed node)
        }
    } else {
        #pragma unroll
        for (int s = 0; s < GPB; ++s)
            ah[GPB + s][j] = memory[(size_t)nd[s] * LL + j];
    }
    __syncthreads();

    // Gate-split matvec: g0 -> wih vs agg, g1 -> whh vs h (LDS rows).
    const uint4* wpb = (const uint4*)(ws + (g ? OFF_WHHB : OFF_WIHB));
    float a0[GPB] = {}, a1[GPB] = {}, a2[GPB] = {};
    #pragma unroll 2
    for (int k8 = 0; k8 < NK8_2; ++k8) {
        const f8 w0 = unpack8(wpb[(0 * NK8_2 + k8) * LL + j]);
        const f8 w1 = unpack8(wpb[(1 * NK8_2 + k8) * LL + j]);
        const f8 w2 = unpack8(wpb[(2 * NK8_2 + k8) * LL + j]);
        #pragma unroll
        for (int s = 0; s < GPB; ++s) {
            const float4 v0 = *(const float4*)&ah[g * GPB + s][8 * k8];
            const float4 v1 = *(const float4*)&ah[g * GPB + s][8 * k8 + 4];
            const float v[8] = {v0.x, v0.y, v0.z, v0.w, v1.x, v1.y, v1.z, v1.w};
            #pragma unroll
            for (int c = 0; c < 8; ++c) {
                a0[s] = fmaf(w0.v[c], v[c], a0[s]);
                a1[s] = fmaf(w1.v[c], v[c], a1[s]);
                a2[s] = fmaf(w2.v[c], v[c], a2[s]);
            }
        }
    }
    #pragma unroll
    for (int s = 0; s < GPB; ++s) {
        gates[g * 3 + 0][s][j] = a0[s];
        gates[g * 3 + 1][s][j] = a1[s];
        gates[g * 3 + 2][s][j] = a2[s];
    }
    __syncthreads();

    // Finalize; h from LDS.
    const int total = nact * LL;
    for (int o = tid; o < total; o += 256) {
        const int s = o >> 7, jj = o & 127;
        const int node = nodes_sh[s];
        const float ir = gates[0][s][jj] + bih[jj];
        const float iz = gates[1][s][jj] + bih[LL + jj];
        const float inn = gates[2][s][jj] + bih[2 * LL + jj];
        const float hr = gates[3][s][jj] + bhh[jj];
        const float hz = gates[4][s][jj] + bhh[LL + jj];
        const float hn = gates[5][s][jj] + bhh[2 * LL + jj];
        const float r = 1.0f / (1.0f + __expf(-(ir + hr)));
        const float z = 1.0f / (1.0f + __expf(-(iz + hz)));
        const float n = tanhf(inn + r * hn);
        const float h = ah[GPB + s][jj];
        out[(size_t)node * LL + jj] = (1.0f - z) * n + z * h;
    }
}

// ---------------------------------------------------------------------------
extern "C" void kernel_launch(void* const* d_in, const int* in_sizes, int n_in,
                              void* d_out, int out_size, void* d_ws, size_t ws_size,
                              hipStream_t stream) {
    const float* x        = (const float*)d_in[0];
    const float* memory   = (const float*)d_in[1];
    const float* delta_t  = (const float*)d_in[2];
    const float* src_w1   = (const float*)d_in[3];
    const float* src_b1   = (const float*)d_in[4];
    const float* src_w2   = (const float*)d_in[5];
    const float* src_b2   = (const float*)d_in[6];
    const float* tar_w1   = (const float*)d_in[7];
    const float* tar_b1   = (const float*)d_in[8];
    const float* tar_w2   = (const float*)d_in[9];
    const float* tar_b2   = (const float*)d_in[10];
    const float* gru_wih  = (const float*)d_in[11];
    const float* gru_whh  = (const float*)d_in[12];
    const float* gru_bih  = (const float*)d_in[13];
    const float* gru_bhh  = (const float*)d_in[14];
    const int*   source   = (const int*)d_in[15];
    const int*   target   = (const int*)d_in[16];

    float* out = (float*)d_out;
    float* ws  = (float*)d_ws;

    // 1) prep: head fill + w1/w2 bf16-pack (edge prereqs only)
    prep_kernel<<<128, 256, 0, stream>>>(
        src_w1, tar_w1, src_w2, tar_w2, ws);

    // 2) edge messages (256 blocks, EPB=4) + copy (16) + gru pack (24)
    edge_msg_kernel<<<296, 512, 0, stream>>>(
        x, memory, delta_t, src_b1, src_b2, tar_b1, tar_b2,
        gru_wih, gru_whh, source, target, ws, out);

    // 3) GRU over compact seen list (256 blocks, GPB=4, chain aggregation)
    gru_kernel<<<1024 / GPB, 256, 0, stream>>>(
        memory, gru_bih, gru_bhh, ws, out);
}